// Round 19
// baseline (357.213 us; speedup 1.0000x reference)
//
#include <hip/hip_runtime.h>

#define B_ 64
#define T_ 512
#define I_ 128
#define H_ 1024
#define O_ 128

typedef unsigned short u16;
typedef unsigned int u32;
typedef __attribute__((ext_vector_type(8))) short short8v;
typedef __attribute__((ext_vector_type(4))) float float4v;

typedef __attribute__((address_space(1))) const void gvoid_t;
typedef __attribute__((address_space(3))) void svoid_t;

__device__ __forceinline__ u16 f2bf(float f) {
  union { float f; u32 u; } v; v.f = f;
  u32 r = v.u + 0x7FFF + ((v.u >> 16) & 1);
  return (u16)(r >> 16);
}
__device__ __forceinline__ float bf2f(u16 b) {
  union { u32 u; float f; } v; v.u = ((u32)b) << 16;
  return v.f;
}
__device__ __forceinline__ float bits2f(u32 b) {
  union { u32 u; float f; } v; v.u = b;
  return v.f;
}

__device__ __forceinline__ float fwht32(float x, int lane) {
#pragma unroll
  for (int s = 1; s <= 16; s <<= 1) {
    const float y = __shfl_xor(x, s);
    x = (lane & s) ? (y - x) : (x + y);
  }
  return x;
}

__device__ __forceinline__ void fwht32_reg(float* x) {
#pragma unroll
  for (int s = 1; s < 32; s <<= 1)
#pragma unroll
    for (int i = 0; i < 32; ++i)
      if (!(i & s)) { const float a = x[i], b = x[i | s]; x[i] = a + b; x[i | s] = a - b; }
}

__device__ __forceinline__ void transpose32(float* x, float (*T)[33], int t) {
#pragma unroll
  for (int c = 0; c < 32; ++c) T[t][c] = x[c];
#pragma unroll
  for (int c = 0; c < 32; ++c) x[c] = T[c][t];
}

// ---- fused prep: [0,1024) Wbn 32x32 tiled transpose; [1024,1152) W_in tiles; rest xT ----
__global__ __launch_bounds__(256) void prep_all(const float* __restrict__ x, const float* __restrict__ Wbn,
                                                const float* __restrict__ W_in, u16* __restrict__ xT,
                                                u16* __restrict__ WbnT, u16* __restrict__ WinT) {
  __shared__ float tl[32][33];
  const int blk = blockIdx.x;
  const int tid = threadIdx.x;
  if (blk < 1024) {
    const int bx = blk & 31, by = blk >> 5;
    const int c = tid & 31, r8 = tid >> 5;
#pragma unroll
    for (int i = 0; i < 4; ++i) {
      const int r = r8 + i * 8;
      tl[r][c] = Wbn[(size_t)(by * 32 + r) * 1024 + bx * 32 + c];
    }
    __syncthreads();
#pragma unroll
    for (int i = 0; i < 4; ++i) {
      const int r = r8 + i * 8;
      WbnT[(size_t)(bx * 32 + r) * 1024 + by * 32 + c] = f2bf(tl[c][r]);
    }
  } else if (blk < 1152) {
    const int t2 = blk - 1024;
    const int bx = t2 & 31, by = t2 >> 5;
    const int c = tid & 31, r8 = tid >> 5;
#pragma unroll
    for (int i = 0; i < 4; ++i) {
      const int r = r8 + i * 8;
      tl[r][c] = W_in[(size_t)(by * 32 + r) * 1024 + bx * 32 + c];
    }
    __syncthreads();
#pragma unroll
    for (int i = 0; i < 4; ++i) {
      const int r = r8 + i * 8;
      WinT[(size_t)(bx * 32 + r) * 128 + by * 32 + c] = f2bf(tl[c][r]);
    }
  } else {
    const int idx = (blk - 1152) * 256 + tid;
    const int i = idx & (I_ - 1);
    const int r = idx >> 7;
    const int b = r & (B_ - 1);
    const int t = r >> 6;
    xT[idx] = f2bf(x[((size_t)b * T_ + t) * I_ + i]);
  }
}

// ---- pipelined m97 GEMM: 128M x 256N, 8 waves, BK=64, LDS double-buffer (96KB, 1 blk/CU).
//      T3 minimum-2-phase: stage(kt+1 -> buf^1) at iter top; ONE vmcnt(0)+s_barrier per tile.
//      Safety: all ds_read values consumed by MFMA in-iteration (lgkm-drained) before barrier,
//      so the next iteration's stage into that buffer cannot race. ----
template <int K, bool BIAS>
__global__ __launch_bounds__(512) void gemm_bf16(const u16* __restrict__ A, const u16* __restrict__ Bt,
                                                 u16* __restrict__ C, const float* __restrict__ bias) {
  __shared__ u16 As[2][128 * 64];   // 2 x 16KB
  __shared__ u16 Bs[2][256 * 64];   // 2 x 32KB
  const int tid = threadIdx.x;
  const int bm = blockIdx.x, bn = blockIdx.y;
  const int lane = tid & 63, w = tid >> 6;
  const int wr = w >> 2, wc = w & 3;
  const int l16 = lane & 15, lq = lane >> 4;

  float4v acc[4][4];
#pragma unroll
  for (int mi = 0; mi < 4; ++mi)
#pragma unroll
    for (int ni = 0; ni < 4; ++ni)
#pragma unroll
      for (int j = 0; j < 4; ++j) acc[mi][ni][j] = 0.f;

  const int lrow = lane >> 3;
  const int scol = (((lane & 7) ^ lrow) << 3);
  const u16* Ag = A + (size_t)(bm * 128 + w * 16 + lrow) * K + scol;
  const u16* Bg = Bt + (size_t)(bn * 256 + w * 32 + lrow) * K + scol;

#define STAGE(buf, k0)                                                                   \
  {                                                                                      \
    _Pragma("unroll") for (int i = 0; i < 2; ++i)                                        \
        __builtin_amdgcn_global_load_lds((gvoid_t*)(Ag + (k0) + (size_t)i * 8 * K),      \
                                         (svoid_t*)&As[buf][(w * 16 + i * 8) * 64], 16, 0, 0); \
    _Pragma("unroll") for (int i = 0; i < 4; ++i)                                        \
        __builtin_amdgcn_global_load_lds((gvoid_t*)(Bg + (k0) + (size_t)i * 8 * K),      \
                                         (svoid_t*)&Bs[buf][(w * 32 + i * 8) * 64], 16, 0, 0); \
  }

  // prologue: stage tile 0 and drain
  STAGE(0, 0);
  asm volatile("s_waitcnt vmcnt(0)" ::: "memory");
  __builtin_amdgcn_sched_barrier(0);
  __builtin_amdgcn_s_barrier();

  const int NT = K / 64;
  for (int kt = 0; kt < NT; ++kt) {
    const int cur = kt & 1;
    if (kt + 1 < NT) STAGE((kt + 1) & 1, (kt + 1) * 64);
    __builtin_amdgcn_sched_barrier(0);   // pin stage issuance before compute
#pragma unroll
    for (int ks = 0; ks < 2; ++ks) {
      short8v a[4], bf[4];
#pragma unroll
      for (int mi = 0; mi < 4; ++mi) {
        const int row = wr * 64 + mi * 16 + l16;
        a[mi] = *(const short8v*)&As[cur][row * 64 + (((ks * 4 + lq) ^ (row & 7)) << 3)];
      }
#pragma unroll
      for (int ni = 0; ni < 4; ++ni) {
        const int row = wc * 64 + ni * 16 + l16;
        bf[ni] = *(const short8v*)&Bs[cur][row * 64 + (((ks * 4 + lq) ^ (row & 7)) << 3)];
      }
#pragma unroll
      for (int mi = 0; mi < 4; ++mi)
#pragma unroll
        for (int ni = 0; ni < 4; ++ni)
          acc[mi][ni] = __builtin_amdgcn_mfma_f32_16x16x32_bf16(a[mi], bf[ni], acc[mi][ni], 0, 0, 0);
    }
    asm volatile("s_waitcnt vmcnt(0)" ::: "memory");   // own stage loads landed
    __builtin_amdgcn_sched_barrier(0);
    __builtin_amdgcn_s_barrier();                      // all waves' loads landed
  }
#undef STAGE

#pragma unroll
  for (int mi = 0; mi < 4; ++mi)
#pragma unroll
    for (int ni = 0; ni < 4; ++ni) {
      const int row = bm * 128 + wr * 64 + mi * 16 + lq * 4;
      const int col = bn * 256 + wc * 64 + ni * 16 + l16;
      const float bv = BIAS ? bias[col] : 0.f;
#pragma unroll
      for (int j = 0; j < 4; ++j) C[(size_t)(row + j) * H_ + col] = f2bf(acc[mi][ni][j] + bv);
    }
}

// ---- Pinit: P[hb] = L^16 ----
__global__ __launch_bounds__(1024) void h1_Pinit(const float* __restrict__ s1, float* __restrict__ P) {
  const int hb = blockIdx.x;
  const int tid = threadIdx.x;
  const int j = tid >> 5, r = tid & 31;
  const int lane = tid & 63;
  const float sc = s1[hb * 32 + r] * 0.17677669529663687f;
  float x = (r == j) ? 1.f : 0.f;
  for (int it = 0; it < 16; ++it) x = sc * fwht32(x, lane);
  P[(size_t)hb * 1024 + r * 32 + j] = x;
}

// ---- h1 pass A: 32 chunks of 16 steps; per-thread 32-elem block state, no DS ops ----
__global__ __launch_bounds__(64) void h1_local(const u16* __restrict__ u, const float* __restrict__ s1,
                                               float* __restrict__ Ybuf) {
  const int g = blockIdx.x * 64 + threadIdx.x;
  const int hb = g & 31, b = (g >> 5) & 63, chunk = g >> 11;
  float x[32], sc[32];
#pragma unroll
  for (int i = 0; i < 32; i += 4) {
    const float4 s4 = *(const float4*)&s1[hb * 32 + i];
    sc[i] = s4.x * 0.17677669529663687f;
    sc[i + 1] = s4.y * 0.17677669529663687f;
    sc[i + 2] = s4.z * 0.17677669529663687f;
    sc[i + 3] = s4.w * 0.17677669529663687f;
  }
#pragma unroll
  for (int i = 0; i < 32; ++i) x[i] = 0.f;
  const u16* up = u + ((size_t)(chunk * 16) * B_ + b) * H_ + hb * 32;
#pragma unroll 2
  for (int k = 0; k < 16; ++k) {
    u32 wv[16];
#pragma unroll
    for (int j = 0; j < 4; ++j) {
      const uint4 t4 = *(const uint4*)(up + (size_t)k * (B_ * H_) + j * 8);
      wv[4 * j] = t4.x; wv[4 * j + 1] = t4.y; wv[4 * j + 2] = t4.z; wv[4 * j + 3] = t4.w;
    }
    fwht32_reg(x);
#pragma unroll
    for (int i2 = 0; i2 < 16; ++i2) {
      x[2 * i2]     = fmaf(sc[2 * i2],     x[2 * i2],     bits2f(wv[i2] << 16));
      x[2 * i2 + 1] = fmaf(sc[2 * i2 + 1], x[2 * i2 + 1], bits2f(wv[i2] & 0xFFFF0000u));
    }
  }
  float* yp = Ybuf + (size_t)g * 32;
#pragma unroll
  for (int i = 0; i < 32; i += 4) {
    float4 o; o.x = x[i]; o.y = x[i + 1]; o.z = x[i + 2]; o.w = x[i + 3];
    *(float4*)(yp + i) = o;
  }
}

// ---- h1 carry: Z_0 = 0; Z_{c+1} = P·Z_c + y_c over 32 chunks. Grid (hpair, b), 1 wave. ----
__global__ __launch_bounds__(64) void h1_carry(const float* __restrict__ P, const float* __restrict__ Ybuf,
                                               float* __restrict__ Zbuf) {
  const int hpair = blockIdx.x, b = blockIdx.y;
  const int lane = threadIdx.x;
  const int r = lane & 31, hb = hpair * 2 + (lane >> 5);
  const float* Prow = P + (size_t)hb * 1024 + r * 32;
  float pr[32];
#pragma unroll
  for (int j = 0; j < 32; ++j) pr[j] = Prow[j];
  float z = 0.f;
  const int base = lane & 32;
  for (int c = 0; c < 32; ++c) {
    Zbuf[(((size_t)c * 64 + b) * 32 + hb) * 32 + r] = z;
    if (c < 31) {
      const float yv = Ybuf[(((size_t)c * 64 + b) * 32 + hb) * 32 + r];
      float zn = 0.f;
#pragma unroll
      for (int j = 0; j < 32; ++j) zn = fmaf(pr[j], __shfl(z, base + j), zn);
      z = zn + yv;
    }
  }
}

// ---- h1 pass C: re-run 16-step scan seeded with Z_c; write relu(h1) bf16 in place ----
__global__ __launch_bounds__(64) void h1_apply(u16* __restrict__ u, const float* __restrict__ s1,
                                               const float* __restrict__ Zbuf) {
  const int g = blockIdx.x * 64 + threadIdx.x;
  const int hb = g & 31, b = (g >> 5) & 63, chunk = g >> 11;
  float x[32], sc[32];
#pragma unroll
  for (int i = 0; i < 32; i += 4) {
    const float4 s4 = *(const float4*)&s1[hb * 32 + i];
    sc[i] = s4.x * 0.17677669529663687f;
    sc[i + 1] = s4.y * 0.17677669529663687f;
    sc[i + 2] = s4.z * 0.17677669529663687f;
    sc[i + 3] = s4.w * 0.17677669529663687f;
  }
  const float* zp = Zbuf + (size_t)g * 32;
#pragma unroll
  for (int i = 0; i < 32; i += 4) {
    const float4 z4 = *(const float4*)(zp + i);
    x[i] = z4.x; x[i + 1] = z4.y; x[i + 2] = z4.z; x[i + 3] = z4.w;
  }
  u16* up = u + ((size_t)(chunk * 16) * B_ + b) * H_ + hb * 32;
#pragma unroll 2
  for (int k = 0; k < 16; ++k) {
    u32 wv[16];
#pragma unroll
    for (int j = 0; j < 4; ++j) {
      const uint4 t4 = *(const uint4*)(up + (size_t)k * (B_ * H_) + j * 8);
      wv[4 * j] = t4.x; wv[4 * j + 1] = t4.y; wv[4 * j + 2] = t4.z; wv[4 * j + 3] = t4.w;
    }
    fwht32_reg(x);
#pragma unroll
    for (int i2 = 0; i2 < 16; ++i2) {
      x[2 * i2]     = fmaf(sc[2 * i2],     x[2 * i2],     bits2f(wv[i2] << 16));
      x[2 * i2 + 1] = fmaf(sc[2 * i2 + 1], x[2 * i2 + 1], bits2f(wv[i2] & 0xFFFF0000u));
    }
    u32 ov[16];
#pragma unroll
    for (int i2 = 0; i2 < 16; ++i2) {
      const u32 lo = f2bf(fmaxf(x[2 * i2], 0.f));
      const u32 hi = f2bf(fmaxf(x[2 * i2 + 1], 0.f));
      ov[i2] = lo | (hi << 16);
    }
#pragma unroll
    for (int j = 0; j < 4; ++j) {
      uint4 t4; t4.x = ov[4 * j]; t4.y = ov[4 * j + 1]; t4.z = ov[4 * j + 2]; t4.w = ov[4 * j + 3];
      *(uint4*)(up + (size_t)k * (B_ * H_) + j * 8) = t4;
    }
  }
}

// ---- fwht_chunk, Kronecker form (R12-verified): A32 rows + 16x32 Y chunk scans ----
__global__ __launch_bounds__(256) void fwht_chunk(const u16* __restrict__ V, const float* __restrict__ s2,
                                                  u16* __restrict__ A32, u16* __restrict__ Y) {
  __shared__ float tr[4][2][32][33];
  const int wv = threadIdx.x >> 6;
  const int lane = threadIdx.x & 63;
  const int slot = lane >> 5, t = lane & 31;
  float (*T)[33] = tr[wv][slot];
  const int gs = blockIdx.x * 8 + wv * 2 + slot;

  float x[32], s0[32], s1[32];
#pragma unroll
  for (int c = 0; c < 32; ++c) {
    s0[c] = s2[t * 32 + c] * 0.03125f;
    s1[c] = s2[c * 32 + t] * 0.03125f;
  }

  if (gs < 1024) {
    const int W = gs;
#pragma unroll
    for (int c = 0; c < 32; ++c) x[c] = (t * 32 + c == W) ? 1.f : 0.f;
    for (int j = 0; j < 32; ++j) {
      if (j & 1) {
#pragma unroll
        for (int c = 0; c < 32; ++c) x[c] *= s1[c];
      } else {
#pragma unroll
        for (int c = 0; c < 32; ++c) x[c] *= s0[c];
      }
      fwht32_reg(x);
      transpose32(x, T, t);
      fwht32_reg(x);
    }
    u16* dst = A32 + (size_t)W * H_ + t * 32;
    u32 ov[16];
#pragma unroll
    for (int c = 0; c < 16; ++c) ov[c] = (u32)f2bf(x[2 * c]) | ((u32)f2bf(x[2 * c + 1]) << 16);
#pragma unroll
    for (int j = 0; j < 4; ++j) {
      uint4 t4; t4.x = ov[4 * j]; t4.y = ov[4 * j + 1]; t4.z = ov[4 * j + 2]; t4.w = ov[4 * j + 3];
      *(uint4*)(dst + j * 8) = t4;
    }
  } else {
    const int s = gs - 1024;
    const int c0 = s >> 6, b = s & 63;
    const u16* Vbase = V + ((size_t)(c0 * 32) * B_ + b) * H_;
#pragma unroll
    for (int c = 0; c < 32; ++c) x[c] = 0.f;
    for (int j = 0; j < 32; ++j) {
      const u16* vrow = Vbase + (size_t)j * (B_ * H_);
      const int pe = (j + 1) & 1;
      u32 vpk[16];
      u16 vsc[32];
      if (pe == 0) {
#pragma unroll
        for (int q = 0; q < 4; ++q) {
          const uint4 t4 = *(const uint4*)(vrow + t * 32 + q * 8);
          vpk[4 * q] = t4.x; vpk[4 * q + 1] = t4.y; vpk[4 * q + 2] = t4.z; vpk[4 * q + 3] = t4.w;
        }
      } else {
#pragma unroll
        for (int c = 0; c < 32; ++c) vsc[c] = vrow[c * 32 + t];
      }
      fwht32_reg(x);
      transpose32(x, T, t);
      fwht32_reg(x);
      if (pe == 0) {
#pragma unroll
        for (int c = 0; c < 16; ++c) {
          x[2 * c]     = fmaf(s0[2 * c],     x[2 * c],     bits2f(vpk[c] << 16));
          x[2 * c + 1] = fmaf(s0[2 * c + 1], x[2 * c + 1], bits2f(vpk[c] & 0xFFFF0000u));
        }
      } else {
#pragma unroll
        for (int c = 0; c < 32; ++c) x[c] = fmaf(s1[c], x[c], bf2f(vsc[c]));
      }
    }
    u16* dst = Y + ((size_t)c0 * B_ + b) * H_ + t * 32;
    u32 ov[16];
#pragma unroll
    for (int c = 0; c < 16; ++c) ov[c] = (u32)f2bf(x[2 * c]) | ((u32)f2bf(x[2 * c + 1]) << 16);
#pragma unroll
    for (int j = 0; j < 4; ++j) {
      uint4 t4; t4.x = ov[4 * j]; t4.y = ov[4 * j + 1]; t4.z = ov[4 * j + 2]; t4.w = ov[4 * j + 3];
      *(uint4*)(dst + j * 8) = t4;
    }
  }
}

// ---- combine stage: Znew[64x1024] = Zold @ (A32)^T + Y_c. ----
template <bool LAST>
__global__ __launch_bounds__(256) void combine(const u16* __restrict__ Zold, const u16* __restrict__ Yc,
                                               const u16* __restrict__ A32, u16* __restrict__ Znew,
                                               float* __restrict__ h2out) {
  const int rt = blockIdx.x >> 6, nt = blockIdx.x & 63;
  const int tid = threadIdx.x;
  __shared__ float red[4][16][16];
  const int w = tid >> 6, lane = tid & 63, l16 = lane & 15, lq = lane >> 4;
  float4v acc = {0.f, 0.f, 0.f, 0.f};
  const u16* Ap = Zold + (size_t)(rt * 16 + l16) * H_ + w * 256 + lq * 8;
  const u16* Bp = A32 + (size_t)(nt * 16 + l16) * H_ + w * 256 + lq * 8;
#pragma unroll
  for (int ks = 0; ks < 8; ++ks) {
    short8v a = *(const short8v*)(Ap + ks * 32);
    short8v bb = *(const short8v*)(Bp + ks * 32);
    acc = __builtin_amdgcn_mfma_f32_16x16x32_bf16(a, bb, acc, 0, 0, 0);
  }
#pragma unroll
  for (int j = 0; j < 4; ++j) red[w][lq * 4 + j][l16] = acc[j];
  __syncthreads();
  const int row = tid >> 4, col = tid & 15;
  float s = red[0][row][col] + red[1][row][col] + red[2][row][col] + red[3][row][col];
  const int b = rt * 16 + row, n = nt * 16 + col;
  s += bf2f(Yc[(size_t)b * H_ + n]);
  if (LAST) h2out[(size_t)b * H_ + n] = s;
  else Znew[(size_t)b * H_ + n] = f2bf(s);
}

// ---- final: out[b][o] = relu(h2[b]) . W_out[:,o] + b_out[o] ----
__global__ __launch_bounds__(128) void final_out(const float* __restrict__ h2, const float* __restrict__ W_out,
                                                 const float* __restrict__ b_out, float* __restrict__ out) {
  __shared__ float hrow[H_];
  const int b = blockIdx.x, o = threadIdx.x;
  for (int i = o; i < H_; i += 128) hrow[i] = fmaxf(h2[(size_t)b * H_ + i], 0.f);
  __syncthreads();
  float acc = b_out[o];
  for (int h = 0; h < H_; ++h) acc = fmaf(hrow[h], W_out[(size_t)h * O_ + o], acc);
  out[b * O_ + o] = acc;
}

extern "C" void kernel_launch(void* const* d_in, const int* in_sizes, int n_in,
                              void* d_out, int out_size, void* d_ws, size_t ws_size,
                              hipStream_t stream) {
  const float* x     = (const float*)d_in[0];
  const float* W_in  = (const float*)d_in[1];
  const float* s1    = (const float*)d_in[2];
  const float* b1    = (const float*)d_in[3];
  const float* s2    = (const float*)d_in[4];
  const float* b2    = (const float*)d_in[5];
  const float* Wbn   = (const float*)d_in[6];
  const float* W_out = (const float*)d_in[7];
  const float* b_out = (const float*)d_in[8];
  float* out = (float*)d_out;

  // workspace layout (identical to R12/R14/R18)
  char* ws = (char*)d_ws;
  u16* u      = (u16*)ws;                    // 64MB
  u16* V      = (u16*)(ws + 67108864);       // 64MB
  float* P1   = (float*)(ws + 67108864);     // 128KB, aliases V head (dead before gemm_V)
  float* Zbuf = (float*)(ws + 69206016);     // 8MB,  aliases V+2MB (dead before gemm_V)
  u16* xT     = (u16*)(ws + 134217728);      // 8MB, dead after gemm_in
  float* Ybuf = (float*)(ws + 134217728);    // 8MB (aliases xT, after gemm_in)
  u16* WbnT   = (u16*)(ws + 142606336);      // 2MB
  u16* WinT   = (u16*)(ws + 144703488);      // 256KB
  u16* A32    = (u16*)(ws + 134217728);      // 2MB (after h1 done)
  u16* Y      = (u16*)(ws + 136314880);      // 2MB ([16][64][1024] bf16)
  u16* Zb0    = (u16*)(ws + 138412032);      // 128KB
  u16* Zb1    = (u16*)(ws + 138543104);      // 128KB
  float* h2   = (float*)(ws + 138674176);    // 256KB

  prep_all<<<17536, 256, 0, stream>>>(x, Wbn, W_in, xT, WbnT, WinT);
  h1_Pinit<<<32, 1024, 0, stream>>>(s1, P1);
  gemm_bf16<128, true><<<dim3(256, 4), 512, 0, stream>>>(xT, WinT, u, b1);  // u = x@W_in + b1
  h1_local<<<1024, 64, 0, stream>>>(u, s1, Ybuf);
  h1_carry<<<dim3(16, 64), 64, 0, stream>>>(P1, Ybuf, Zbuf);
  h1_apply<<<1024, 64, 0, stream>>>(u, s1, Zbuf);
  gemm_bf16<1024, true><<<dim3(256, 4), 512, 0, stream>>>(u, WbnT, V, b2);
  fwht_chunk<<<256, 256, 0, stream>>>(V, s2, A32, Y);

  // Horner chain seeded with Zold = Y_0: 15 links.
  const size_t BH = (size_t)B_ * H_;
  const u16* Zcur = Y;
  u16* Zb[2] = {Zb0, Zb1};
  for (int c = 1; c < 15; ++c) {
    u16* Znew = Zb[c & 1];
    combine<false><<<256, 256, 0, stream>>>(Zcur, Y + (size_t)c * BH, A32, Znew, nullptr);
    Zcur = Znew;
  }
  combine<true><<<256, 256, 0, stream>>>(Zcur, Y + (size_t)15 * BH, A32, nullptr, h2);

  final_out<<<64, 128, 0, stream>>>(h2, W_out, b_out, out);
}

// Round 20
// 307.185 us; speedup vs baseline: 1.1629x; 1.1629x over previous
//
#include <hip/hip_runtime.h>

#define B_ 64
#define T_ 512
#define I_ 128
#define H_ 1024
#define O_ 128

typedef unsigned short u16;
typedef unsigned int u32;
typedef __attribute__((ext_vector_type(8))) short short8v;
typedef __attribute__((ext_vector_type(4))) float float4v;

typedef __attribute__((address_space(1))) const void gvoid_t;
typedef __attribute__((address_space(3))) void svoid_t;

__device__ __forceinline__ u16 f2bf(float f) {
  union { float f; u32 u; } v; v.f = f;
  u32 r = v.u + 0x7FFF + ((v.u >> 16) & 1);
  return (u16)(r >> 16);
}
__device__ __forceinline__ float bf2f(u16 b) {
  union { u32 u; float f; } v; v.u = ((u32)b) << 16;
  return v.f;
}
__device__ __forceinline__ float bits2f(u32 b) {
  union { u32 u; float f; } v; v.u = b;
  return v.f;
}

__device__ __forceinline__ float fwht32(float x, int lane) {
#pragma unroll
  for (int s = 1; s <= 16; s <<= 1) {
    const float y = __shfl_xor(x, s);
    x = (lane & s) ? (y - x) : (x + y);
  }
  return x;
}

__device__ __forceinline__ void fwht32_reg(float* x) {
#pragma unroll
  for (int s = 1; s < 32; s <<= 1)
#pragma unroll
    for (int i = 0; i < 32; ++i)
      if (!(i & s)) { const float a = x[i], b = x[i | s]; x[i] = a + b; x[i | s] = a - b; }
}

__device__ __forceinline__ void transpose32(float* x, float (*T)[33], int t) {
#pragma unroll
  for (int c = 0; c < 32; ++c) T[t][c] = x[c];
#pragma unroll
  for (int c = 0; c < 32; ++c) x[c] = T[c][t];
}

// ---- fused prep: [0,1024) Wbn 32x32 tiled transpose; [1024,1152) W_in tiles; rest xT ----
__global__ __launch_bounds__(256) void prep_all(const float* __restrict__ x, const float* __restrict__ Wbn,
                                                const float* __restrict__ W_in, u16* __restrict__ xT,
                                                u16* __restrict__ WbnT, u16* __restrict__ WinT) {
  __shared__ float tl[32][33];
  const int blk = blockIdx.x;
  const int tid = threadIdx.x;
  if (blk < 1024) {
    const int bx = blk & 31, by = blk >> 5;
    const int c = tid & 31, r8 = tid >> 5;
#pragma unroll
    for (int i = 0; i < 4; ++i) {
      const int r = r8 + i * 8;
      tl[r][c] = Wbn[(size_t)(by * 32 + r) * 1024 + bx * 32 + c];
    }
    __syncthreads();
#pragma unroll
    for (int i = 0; i < 4; ++i) {
      const int r = r8 + i * 8;
      WbnT[(size_t)(bx * 32 + r) * 1024 + by * 32 + c] = f2bf(tl[c][r]);
    }
  } else if (blk < 1152) {
    const int t2 = blk - 1024;
    const int bx = t2 & 31, by = t2 >> 5;
    const int c = tid & 31, r8 = tid >> 5;
#pragma unroll
    for (int i = 0; i < 4; ++i) {
      const int r = r8 + i * 8;
      tl[r][c] = W_in[(size_t)(by * 32 + r) * 1024 + bx * 32 + c];
    }
    __syncthreads();
#pragma unroll
    for (int i = 0; i < 4; ++i) {
      const int r = r8 + i * 8;
      WinT[(size_t)(bx * 32 + r) * 128 + by * 32 + c] = f2bf(tl[c][r]);
    }
  } else {
    const int idx = (blk - 1152) * 256 + tid;
    const int i = idx & (I_ - 1);
    const int r = idx >> 7;
    const int b = r & (B_ - 1);
    const int t = r >> 6;
    xT[idx] = f2bf(x[((size_t)b * T_ + t) * I_ + i]);
  }
}

// ---- widened m97 GEMM: 128M x 256N, 8 waves, BK=64 (R14-verified) ----
template <int K, bool BIAS>
__global__ __launch_bounds__(512) void gemm_bf16(const u16* __restrict__ A, const u16* __restrict__ Bt,
                                                 u16* __restrict__ C, const float* __restrict__ bias) {
  __shared__ u16 As[128 * 64];
  __shared__ u16 Bs[256 * 64];
  const int tid = threadIdx.x;
  const int bm = blockIdx.x, bn = blockIdx.y;
  const int lane = tid & 63, w = tid >> 6;
  const int wr = w >> 2, wc = w & 3;
  const int l16 = lane & 15, lq = lane >> 4;

  float4v acc[4][4];
#pragma unroll
  for (int mi = 0; mi < 4; ++mi)
#pragma unroll
    for (int ni = 0; ni < 4; ++ni)
#pragma unroll
      for (int j = 0; j < 4; ++j) acc[mi][ni][j] = 0.f;

  const int lrow = lane >> 3;
  const int scol = (((lane & 7) ^ lrow) << 3);
  const u16* Ag = A + (size_t)(bm * 128 + w * 16 + lrow) * K + scol;
  const u16* Bg = Bt + (size_t)(bn * 256 + w * 32 + lrow) * K + scol;

  for (int k0 = 0; k0 < K; k0 += 64) {
    __syncthreads();
#pragma unroll
    for (int i = 0; i < 2; ++i)
      __builtin_amdgcn_global_load_lds((gvoid_t*)(Ag + k0 + (size_t)i * 8 * K),
                                       (svoid_t*)&As[(w * 16 + i * 8) * 64], 16, 0, 0);
#pragma unroll
    for (int i = 0; i < 4; ++i)
      __builtin_amdgcn_global_load_lds((gvoid_t*)(Bg + k0 + (size_t)i * 8 * K),
                                       (svoid_t*)&Bs[(w * 32 + i * 8) * 64], 16, 0, 0);
    __syncthreads();
#pragma unroll
    for (int ks = 0; ks < 2; ++ks) {
      short8v a[4], bf[4];
#pragma unroll
      for (int mi = 0; mi < 4; ++mi) {
        const int row = wr * 64 + mi * 16 + l16;
        a[mi] = *(const short8v*)&As[row * 64 + (((ks * 4 + lq) ^ (row & 7)) << 3)];
      }
#pragma unroll
      for (int ni = 0; ni < 4; ++ni) {
        const int row = wc * 64 + ni * 16 + l16;
        bf[ni] = *(const short8v*)&Bs[row * 64 + (((ks * 4 + lq) ^ (row & 7)) << 3)];
      }
#pragma unroll
      for (int mi = 0; mi < 4; ++mi)
#pragma unroll
        for (int ni = 0; ni < 4; ++ni)
          acc[mi][ni] = __builtin_amdgcn_mfma_f32_16x16x32_bf16(a[mi], bf[ni], acc[mi][ni], 0, 0, 0);
    }
  }

#pragma unroll
  for (int mi = 0; mi < 4; ++mi)
#pragma unroll
    for (int ni = 0; ni < 4; ++ni) {
      const int row = bm * 128 + wr * 64 + mi * 16 + lq * 4;
      const int col = bn * 256 + wc * 64 + ni * 16 + l16;
      const float bv = BIAS ? bias[col] : 0.f;
#pragma unroll
      for (int j = 0; j < 4; ++j) C[(size_t)(row + j) * H_ + col] = f2bf(acc[mi][ni][j] + bv);
    }
}

// ---- Pinit: P[hb] = L^16 ----
__global__ __launch_bounds__(1024) void h1_Pinit(const float* __restrict__ s1, float* __restrict__ P) {
  const int hb = blockIdx.x;
  const int tid = threadIdx.x;
  const int j = tid >> 5, r = tid & 31;
  const int lane = tid & 63;
  const float sc = s1[hb * 32 + r] * 0.17677669529663687f;
  float x = (r == j) ? 1.f : 0.f;
  for (int it = 0; it < 16; ++it) x = sc * fwht32(x, lane);
  P[(size_t)hb * 1024 + r * 32 + j] = x;
}

// ---- h1 pass A: 32 chunks of 16 steps; per-thread 32-elem block state, no DS ops ----
__global__ __launch_bounds__(64) void h1_local(const u16* __restrict__ u, const float* __restrict__ s1,
                                               float* __restrict__ Ybuf) {
  const int g = blockIdx.x * 64 + threadIdx.x;
  const int hb = g & 31, b = (g >> 5) & 63, chunk = g >> 11;
  float x[32], sc[32];
#pragma unroll
  for (int i = 0; i < 32; i += 4) {
    const float4 s4 = *(const float4*)&s1[hb * 32 + i];
    sc[i] = s4.x * 0.17677669529663687f;
    sc[i + 1] = s4.y * 0.17677669529663687f;
    sc[i + 2] = s4.z * 0.17677669529663687f;
    sc[i + 3] = s4.w * 0.17677669529663687f;
  }
#pragma unroll
  for (int i = 0; i < 32; ++i) x[i] = 0.f;
  const u16* up = u + ((size_t)(chunk * 16) * B_ + b) * H_ + hb * 32;
#pragma unroll 2
  for (int k = 0; k < 16; ++k) {
    u32 wv[16];
#pragma unroll
    for (int j = 0; j < 4; ++j) {
      const uint4 t4 = *(const uint4*)(up + (size_t)k * (B_ * H_) + j * 8);
      wv[4 * j] = t4.x; wv[4 * j + 1] = t4.y; wv[4 * j + 2] = t4.z; wv[4 * j + 3] = t4.w;
    }
    fwht32_reg(x);
#pragma unroll
    for (int i2 = 0; i2 < 16; ++i2) {
      x[2 * i2]     = fmaf(sc[2 * i2],     x[2 * i2],     bits2f(wv[i2] << 16));
      x[2 * i2 + 1] = fmaf(sc[2 * i2 + 1], x[2 * i2 + 1], bits2f(wv[i2] & 0xFFFF0000u));
    }
  }
  float* yp = Ybuf + (size_t)g * 32;
#pragma unroll
  for (int i = 0; i < 32; i += 4) {
    float4 o; o.x = x[i]; o.y = x[i + 1]; o.z = x[i + 2]; o.w = x[i + 3];
    *(float4*)(yp + i) = o;
  }
}

// ---- h1 carry: Z_0 = 0; Z_{c+1} = P·Z_c + y_c over 32 chunks. Grid (hpair, b), 1 wave. ----
__global__ __launch_bounds__(64) void h1_carry(const float* __restrict__ P, const float* __restrict__ Ybuf,
                                               float* __restrict__ Zbuf) {
  const int hpair = blockIdx.x, b = blockIdx.y;
  const int lane = threadIdx.x;
  const int r = lane & 31, hb = hpair * 2 + (lane >> 5);
  const float* Prow = P + (size_t)hb * 1024 + r * 32;
  float pr[32];
#pragma unroll
  for (int j = 0; j < 32; ++j) pr[j] = Prow[j];
  float z = 0.f;
  const int base = lane & 32;
  for (int c = 0; c < 32; ++c) {
    Zbuf[(((size_t)c * 64 + b) * 32 + hb) * 32 + r] = z;
    if (c < 31) {
      const float yv = Ybuf[(((size_t)c * 64 + b) * 32 + hb) * 32 + r];
      float zn = 0.f;
#pragma unroll
      for (int j = 0; j < 32; ++j) zn = fmaf(pr[j], __shfl(z, base + j), zn);
      z = zn + yv;
    }
  }
}

// ---- h1 pass C: re-run 16-step scan seeded with Z_c; write relu(h1) bf16 in place ----
__global__ __launch_bounds__(64) void h1_apply(u16* __restrict__ u, const float* __restrict__ s1,
                                               const float* __restrict__ Zbuf) {
  const int g = blockIdx.x * 64 + threadIdx.x;
  const int hb = g & 31, b = (g >> 5) & 63, chunk = g >> 11;
  float x[32], sc[32];
#pragma unroll
  for (int i = 0; i < 32; i += 4) {
    const float4 s4 = *(const float4*)&s1[hb * 32 + i];
    sc[i] = s4.x * 0.17677669529663687f;
    sc[i + 1] = s4.y * 0.17677669529663687f;
    sc[i + 2] = s4.z * 0.17677669529663687f;
    sc[i + 3] = s4.w * 0.17677669529663687f;
  }
  const float* zp = Zbuf + (size_t)g * 32;
#pragma unroll
  for (int i = 0; i < 32; i += 4) {
    const float4 z4 = *(const float4*)(zp + i);
    x[i] = z4.x; x[i + 1] = z4.y; x[i + 2] = z4.z; x[i + 3] = z4.w;
  }
  u16* up = u + ((size_t)(chunk * 16) * B_ + b) * H_ + hb * 32;
#pragma unroll 2
  for (int k = 0; k < 16; ++k) {
    u32 wv[16];
#pragma unroll
    for (int j = 0; j < 4; ++j) {
      const uint4 t4 = *(const uint4*)(up + (size_t)k * (B_ * H_) + j * 8);
      wv[4 * j] = t4.x; wv[4 * j + 1] = t4.y; wv[4 * j + 2] = t4.z; wv[4 * j + 3] = t4.w;
    }
    fwht32_reg(x);
#pragma unroll
    for (int i2 = 0; i2 < 16; ++i2) {
      x[2 * i2]     = fmaf(sc[2 * i2],     x[2 * i2],     bits2f(wv[i2] << 16));
      x[2 * i2 + 1] = fmaf(sc[2 * i2 + 1], x[2 * i2 + 1], bits2f(wv[i2] & 0xFFFF0000u));
    }
    u32 ov[16];
#pragma unroll
    for (int i2 = 0; i2 < 16; ++i2) {
      const u32 lo = f2bf(fmaxf(x[2 * i2], 0.f));
      const u32 hi = f2bf(fmaxf(x[2 * i2 + 1], 0.f));
      ov[i2] = lo | (hi << 16);
    }
#pragma unroll
    for (int j = 0; j < 4; ++j) {
      uint4 t4; t4.x = ov[4 * j]; t4.y = ov[4 * j + 1]; t4.z = ov[4 * j + 2]; t4.w = ov[4 * j + 3];
      *(uint4*)(up + (size_t)k * (B_ * H_) + j * 8) = t4;
    }
  }
}

// ---- fwht_chunk, Kronecker form (R12-verified): A32 rows + 16x32 Y chunk scans ----
__global__ __launch_bounds__(256) void fwht_chunk(const u16* __restrict__ V, const float* __restrict__ s2,
                                                  u16* __restrict__ A32, u16* __restrict__ Y) {
  __shared__ float tr[4][2][32][33];
  const int wv = threadIdx.x >> 6;
  const int lane = threadIdx.x & 63;
  const int slot = lane >> 5, t = lane & 31;
  float (*T)[33] = tr[wv][slot];
  const int gs = blockIdx.x * 8 + wv * 2 + slot;

  float x[32], s0[32], s1[32];
#pragma unroll
  for (int c = 0; c < 32; ++c) {
    s0[c] = s2[t * 32 + c] * 0.03125f;
    s1[c] = s2[c * 32 + t] * 0.03125f;
  }

  if (gs < 1024) {
    const int W = gs;
#pragma unroll
    for (int c = 0; c < 32; ++c) x[c] = (t * 32 + c == W) ? 1.f : 0.f;
    for (int j = 0; j < 32; ++j) {
      if (j & 1) {
#pragma unroll
        for (int c = 0; c < 32; ++c) x[c] *= s1[c];
      } else {
#pragma unroll
        for (int c = 0; c < 32; ++c) x[c] *= s0[c];
      }
      fwht32_reg(x);
      transpose32(x, T, t);
      fwht32_reg(x);
    }
    u16* dst = A32 + (size_t)W * H_ + t * 32;
    u32 ov[16];
#pragma unroll
    for (int c = 0; c < 16; ++c) ov[c] = (u32)f2bf(x[2 * c]) | ((u32)f2bf(x[2 * c + 1]) << 16);
#pragma unroll
    for (int j = 0; j < 4; ++j) {
      uint4 t4; t4.x = ov[4 * j]; t4.y = ov[4 * j + 1]; t4.z = ov[4 * j + 2]; t4.w = ov[4 * j + 3];
      *(uint4*)(dst + j * 8) = t4;
    }
  } else {
    const int s = gs - 1024;
    const int c0 = s >> 6, b = s & 63;
    const u16* Vbase = V + ((size_t)(c0 * 32) * B_ + b) * H_;
#pragma unroll
    for (int c = 0; c < 32; ++c) x[c] = 0.f;
    for (int j = 0; j < 32; ++j) {
      const u16* vrow = Vbase + (size_t)j * (B_ * H_);
      const int pe = (j + 1) & 1;
      u32 vpk[16];
      u16 vsc[32];
      if (pe == 0) {
#pragma unroll
        for (int q = 0; q < 4; ++q) {
          const uint4 t4 = *(const uint4*)(vrow + t * 32 + q * 8);
          vpk[4 * q] = t4.x; vpk[4 * q + 1] = t4.y; vpk[4 * q + 2] = t4.z; vpk[4 * q + 3] = t4.w;
        }
      } else {
#pragma unroll
        for (int c = 0; c < 32; ++c) vsc[c] = vrow[c * 32 + t];
      }
      fwht32_reg(x);
      transpose32(x, T, t);
      fwht32_reg(x);
      if (pe == 0) {
#pragma unroll
        for (int c = 0; c < 16; ++c) {
          x[2 * c]     = fmaf(s0[2 * c],     x[2 * c],     bits2f(vpk[c] << 16));
          x[2 * c + 1] = fmaf(s0[2 * c + 1], x[2 * c + 1], bits2f(vpk[c] & 0xFFFF0000u));
        }
      } else {
#pragma unroll
        for (int c = 0; c < 32; ++c) x[c] = fmaf(s1[c], x[c], bf2f(vsc[c]));
      }
    }
    u16* dst = Y + ((size_t)c0 * B_ + b) * H_ + t * 32;
    u32 ov[16];
#pragma unroll
    for (int c = 0; c < 16; ++c) ov[c] = (u32)f2bf(x[2 * c]) | ((u32)f2bf(x[2 * c + 1]) << 16);
#pragma unroll
    for (int j = 0; j < 4; ++j) {
      uint4 t4; t4.x = ov[4 * j]; t4.y = ov[4 * j + 1]; t4.z = ov[4 * j + 2]; t4.w = ov[4 * j + 3];
      *(uint4*)(dst + j * 8) = t4;
    }
  }
}

// ---- combine stage: Znew[64x1024] = Zold @ (A32)^T + Y_c. ----
template <bool LAST>
__global__ __launch_bounds__(256) void combine(const u16* __restrict__ Zold, const u16* __restrict__ Yc,
                                               const u16* __restrict__ A32, u16* __restrict__ Znew,
                                               float* __restrict__ h2out) {
  const int rt = blockIdx.x >> 6, nt = blockIdx.x & 63;
  const int tid = threadIdx.x;
  __shared__ float red[4][16][16];
  const int w = tid >> 6, lane = tid & 63, l16 = lane & 15, lq = lane >> 4;
  float4v acc = {0.f, 0.f, 0.f, 0.f};
  const u16* Ap = Zold + (size_t)(rt * 16 + l16) * H_ + w * 256 + lq * 8;
  const u16* Bp = A32 + (size_t)(nt * 16 + l16) * H_ + w * 256 + lq * 8;
#pragma unroll
  for (int ks = 0; ks < 8; ++ks) {
    short8v a = *(const short8v*)(Ap + ks * 32);
    short8v bb = *(const short8v*)(Bp + ks * 32);
    acc = __builtin_amdgcn_mfma_f32_16x16x32_bf16(a, bb, acc, 0, 0, 0);
  }
#pragma unroll
  for (int j = 0; j < 4; ++j) red[w][lq * 4 + j][l16] = acc[j];
  __syncthreads();
  const int row = tid >> 4, col = tid & 15;
  float s = red[0][row][col] + red[1][row][col] + red[2][row][col] + red[3][row][col];
  const int b = rt * 16 + row, n = nt * 16 + col;
  s += bf2f(Yc[(size_t)b * H_ + n]);
  if (LAST) h2out[(size_t)b * H_ + n] = s;
  else Znew[(size_t)b * H_ + n] = f2bf(s);
}

// ---- final: out[b][o] = relu(h2[b]) . W_out[:,o] + b_out[o] ----
__global__ __launch_bounds__(128) void final_out(const float* __restrict__ h2, const float* __restrict__ W_out,
                                                 const float* __restrict__ b_out, float* __restrict__ out) {
  __shared__ float hrow[H_];
  const int b = blockIdx.x, o = threadIdx.x;
  for (int i = o; i < H_; i += 128) hrow[i] = fmaxf(h2[(size_t)b * H_ + i], 0.f);
  __syncthreads();
  float acc = b_out[o];
  for (int h = 0; h < H_; ++h) acc = fmaf(hrow[h], W_out[(size_t)h * O_ + o], acc);
  out[b * O_ + o] = acc;
}

extern "C" void kernel_launch(void* const* d_in, const int* in_sizes, int n_in,
                              void* d_out, int out_size, void* d_ws, size_t ws_size,
                              hipStream_t stream) {
  const float* x     = (const float*)d_in[0];
  const float* W_in  = (const float*)d_in[1];
  const float* s1    = (const float*)d_in[2];
  const float* b1    = (const float*)d_in[3];
  const float* s2    = (const float*)d_in[4];
  const float* b2    = (const float*)d_in[5];
  const float* Wbn   = (const float*)d_in[6];
  const float* W_out = (const float*)d_in[7];
  const float* b_out = (const float*)d_in[8];
  float* out = (float*)d_out;

  // workspace layout (identical to R12/R14/R18)
  char* ws = (char*)d_ws;
  u16* u      = (u16*)ws;                    // 64MB
  u16* V      = (u16*)(ws + 67108864);       // 64MB
  float* P1   = (float*)(ws + 67108864);     // 128KB, aliases V head (dead before gemm_V)
  float* Zbuf = (float*)(ws + 69206016);     // 8MB,  aliases V+2MB (dead before gemm_V)
  u16* xT     = (u16*)(ws + 134217728);      // 8MB, dead after gemm_in
  float* Ybuf = (float*)(ws + 134217728);    // 8MB (aliases xT, after gemm_in)
  u16* WbnT   = (u16*)(ws + 142606336);      // 2MB
  u16* WinT   = (u16*)(ws + 144703488);      // 256KB
  u16* A32    = (u16*)(ws + 134217728);      // 2MB (after h1 done)
  u16* Y      = (u16*)(ws + 136314880);      // 2MB ([16][64][1024] bf16)
  u16* Zb0    = (u16*)(ws + 138412032);      // 128KB
  u16* Zb1    = (u16*)(ws + 138543104);      // 128KB
  float* h2   = (float*)(ws + 138674176);    // 256KB

  prep_all<<<17536, 256, 0, stream>>>(x, Wbn, W_in, xT, WbnT, WinT);
  h1_Pinit<<<32, 1024, 0, stream>>>(s1, P1);
  gemm_bf16<128, true><<<dim3(256, 4), 512, 0, stream>>>(xT, WinT, u, b1);  // u = x@W_in + b1
  h1_local<<<1024, 64, 0, stream>>>(u, s1, Ybuf);
  h1_carry<<<dim3(16, 64), 64, 0, stream>>>(P1, Ybuf, Zbuf);
  h1_apply<<<1024, 64, 0, stream>>>(u, s1, Zbuf);
  gemm_bf16<1024, true><<<dim3(256, 4), 512, 0, stream>>>(u, WbnT, V, b2);
  fwht_chunk<<<256, 256, 0, stream>>>(V, s2, A32, Y);

  // Horner chain seeded with Zold = Y_0: 15 links.
  const size_t BH = (size_t)B_ * H_;
  const u16* Zcur = Y;
  u16* Zb[2] = {Zb0, Zb1};
  for (int c = 1; c < 15; ++c) {
    u16* Znew = Zb[c & 1];
    combine<false><<<256, 256, 0, stream>>>(Zcur, Y + (size_t)c * BH, A32, Znew, nullptr);
    Zcur = Znew;
  }
  combine<true><<<256, 256, 0, stream>>>(Zcur, Y + (size_t)15 * BH, A32, nullptr, h2);

  final_out<<<64, 128, 0, stream>>>(h2, W_out, b_out, out);
}